// Round 1
// baseline (27.960 us; speedup 1.0000x reference)
//
#include <hip/hip_runtime.h>

#define C 256
#define HW 81
#define PITCH 266   // ushorts per pixel row: [4 pad][256 ch][6 pad]
#define PITCHD 133  // dwords per pixel row
#define ZROW 81     // zeroed row index for invalid gather taps

__device__ __forceinline__ float lo_f(unsigned int d) {
  union { unsigned int i; float f; } c; c.i = d << 16; return c.f;
}
__device__ __forceinline__ float hi_f(unsigned int d) {
  union { unsigned int i; float f; } c; c.i = d & 0xffff0000u; return c.f;
}
__device__ __forceinline__ float bf2f(unsigned short u) {
  union { unsigned int i; float f; } c; c.i = ((unsigned int)u) << 16; return c.f;
}
__device__ __forceinline__ unsigned short f2bf(float f) {
  union { float f; unsigned int i; } c; c.f = f;
  return (unsigned short)((c.i + 0x7fffu + ((c.i >> 16) & 1u)) >> 16);
}
__device__ __forceinline__ unsigned int pack2(float a, float b) {
  return (unsigned int)f2bf(a) | ((unsigned int)f2bf(b) << 16);
}

// ---------------------------------------------------------------------------
// Fully fused SeMCA. Block = (b, s): s=0 -> output rows 0..5, s=1 -> rows 6..8.
// 1024 threads = 4 instance-slots x 256 channels. 2 barriers.
// R1 changes vs 27.8us baseline:
//  - wv/bv weights in registers (chp fixed per thread) -> kills the 4-way
//    bank-conflicted wvs LDS reads in phase 1b; wvs LDS array removed.
//  - pixtab premultiplied by PITCH (fits u16); per-lane (tap,ci) walk hoisted
//    out of the instance loop -> ~140 fewer VALU ops/thread in phase 2.
//  - 1/ssum via v_rcp_f32 builtin (tolerance 7.8e-3 >> 1e-5 rcp error).
//  - s_setprio(1) around the dense w1/w2/softmax FMA cluster (waves are
//    role-diverse post-barrier; T5 regime).
// ---------------------------------------------------------------------------
__global__ __launch_bounds__(1024) void semca_fused(
    const float* __restrict__ x, const float* __restrict__ wk,
    const float* __restrict__ bk, const float* __restrict__ w1,
    const float* __restrict__ gamma, const float* __restrict__ beta,
    const float* __restrict__ mean, const float* __restrict__ var,
    const float* __restrict__ w2, const float* __restrict__ b2,
    const float* __restrict__ wv, const float* __restrict__ bv,
    float* __restrict__ out) {
  __shared__ unsigned short xT[82 * PITCH];   // 43,624 B (row 81 = zeros)
  __shared__ unsigned short k1T[82 * PITCH];  // 43,624 B (row 81 = zeros)
  __shared__ unsigned short vT[18 * PITCH];   //  9,576 B
  __shared__ unsigned short pixtab[228];      //    456 B (premultiplied by PITCH)
  __shared__ float2 bnf[225];                 //  1,800 B  (~99.1 KiB total)

  const int blk = blockIdx.x;
  const int b = (blk & 7) * 16 + ((blk >> 3) & 15);  // XCD-paired, bijective
  const int s = blk >> 7;
  const int tid = threadIdx.x;
  const float* xb = x + (size_t)b * (C * HW);

  unsigned int* xTd = (unsigned int*)xT;
  unsigned int* k1Td = (unsigned int*)k1T;
  unsigned int* vTd = (unsigned int*)vT;

  // ---- phase 0: stage x (bf16, ch-pair packed dwords), tables, zeros
  {
    auto stage = [&](int f) {
      int chp = f / HW;             // channel pair 0..127 (p consecutive/lane)
      int p = f - chp * HW;
      xTd[PITCHD * p + 2 + chp] =
          pack2(xb[(2 * chp) * HW + p], xb[(2 * chp + 1) * HW + p]);
    };
#pragma unroll
    for (int rep = 0; rep < 10; ++rep) stage(tid + rep * 1024);
    if (tid < 128) stage(10240 + tid);
  }
  for (int t = tid; t < 810; t += 1024) {  // x channel-pad zeros
    int p = t / 10, k2 = t - (t / 10) * 10;
    xT[p * PITCH + ((k2 < 4) ? k2 : (256 + k2))] = 0;
  }
  if (tid < PITCHD) {                      // zero row 81 of xT and k1T
    xTd[PITCHD * ZROW + tid] = 0;
    k1Td[PITCHD * ZROW + tid] = 0;
  }
  for (int t = tid; t < 225; t += 1024) {  // pixtab (premul) + folded BN
    int g = t / 9, tap = t - (t / 9) * 9;
    int kh = tap / 3, kw = tap - kh * 3;
    int h = kh * 5 + g / 5, w = kw * 5 + (g - (g / 5) * 5);
    pixtab[t] = (h < 9 && w < 9) ? (unsigned short)((h * 9 + w) * PITCH)
                                 : (unsigned short)(ZROW * PITCH);
    float inv = gamma[t] * rsqrtf(var[t] + 1e-5f);
    bnf[t] = make_float2(inv, beta[t] - mean[t] * inv);
  }

  // ---- hoisted phase-1b weights: chp is fixed (= tid&127) for every vfn
  // call this thread makes, so wv/bv live in registers, not LDS.
  const int chv = tid & 127;
  float wv_e[9], wv_o[9];
#pragma unroll
  for (int t = 0; t < 9; ++t) {
    wv_e[t] = wv[(2 * chv) * 9 + t];
    wv_o[t] = wv[(2 * chv + 1) * 9 + t];
  }
  const float bv_e = bv[2 * chv], bv_o = bv[2 * chv + 1];

  __syncthreads();

  // ---- phase 1a: k1[p][ch] = sum_j x[p][ch+j-4]*wk[p][j] + bk[p]
  {
    auto k1fn = [&](int f) {
      int p = __builtin_amdgcn_readfirstlane(f >> 7);
      int chp = f & 127;
      const unsigned int* wrow = xTd + PITCHD * p;
      unsigned int d0 = wrow[chp], d1 = wrow[chp + 1], d2 = wrow[chp + 2],
                   d3 = wrow[chp + 3], d4 = wrow[chp + 4];
      float e[10] = {lo_f(d0), hi_f(d0), lo_f(d1), hi_f(d1), lo_f(d2),
                     hi_f(d2), lo_f(d3), hi_f(d3), lo_f(d4), hi_f(d4)};
      const float* wkp = wk + p * 9;  // scalar loads (p uniform)
      float bkp = bk[p];
      float a_e = bkp, a_o = bkp;
#pragma unroll
      for (int j = 0; j < 9; ++j) {
        float wj = wkp[j];
        a_e = fmaf(wj, e[j], a_e);
        a_o = fmaf(wj, e[j + 1], a_o);
      }
      k1Td[PITCHD * p + 2 + chp] = pack2(a_e, a_o);
    };
#pragma unroll
    for (int rep = 0; rep < 10; ++rep) k1fn(tid + rep * 1024);
    if (tid < 128) k1fn(10240 + tid);
  }

  // ---- phase 1b: v (3x3 depthwise) at the 18 pixels this half needs
  {
    auto vfn = [&](int f) {
      int e = __builtin_amdgcn_readfirstlane(f >> 7);  // 0..17 uniform
      int r0 = e / 6;
      int i = s * 3 + r0;  // v-pixel row 0..5
      int j = e - r0 * 6;  // v-pixel col 0..5
      float a_e = bv_e, a_o = bv_o;
#pragma unroll
      for (int di = 0; di < 3; ++di) {
        int ii = i + di - 1;
        if (ii < 0) continue;  // ii <= 6 < 9 always
#pragma unroll
        for (int dj = 0; dj < 3; ++dj) {
          int jj = j + dj - 1;
          if (jj < 0) continue;  // jj <= 6 < 9 always
          unsigned int d = xTd[PITCHD * (ii * 9 + jj) + 2 + chv];
          int t = di * 3 + dj;
          a_e = fmaf(lo_f(d), wv_e[t], a_e);
          a_o = fmaf(hi_f(d), wv_o[t], a_o);
        }
      }
      vTd[PITCHD * e + 2 + chv] = pack2(a_e, a_o);
    };
#pragma unroll
    for (int rep = 0; rep < 2; ++rep) vfn(tid + rep * 1024);
    if (tid < 256) vfn(2048 + tid);
  }
  if (tid < 180) {  // vT channel-pad zeros
    int e = tid / 10, k2 = tid - (tid / 10) * 10;
    vT[e * PITCH + ((k2 < 4) ? k2 : (256 + k2))] = 0;
  }
  __syncthreads();

  // ---- phase 2: 15 deduped instances; 4 slots x 4 unrolled iterations
  const int s4 = tid >> 8;  // slot 0..3 (wave-uniform)
  const int ch = tid & 255;
  const int ci0 = ch / 9;
  const int tap0 = ch - ci0 * 9;
  float* outb = out + ((size_t)b * C + ch) * HW;

  // per-lane gather walk is instance-invariant: hoist out of the k-loop
  int tq[9], cq[9];
  {
    int ci = ci0, tap = tap0;
#pragma unroll
    for (int q = 0; q < 9; ++q) {
      tq[q] = tap;
      cq[q] = 4 + ci;
      tap += 4;
      ci += 28;
      if (tap >= 9) { tap -= 9; ci += 1; }
    }
  }

#define PV_STORE(OH, OW)                                                   \
  do {                                                                     \
    int e_ = gh_i * 6 + ((OW)-3);                                          \
    const unsigned short* vrow_ = vT + e_ * PITCH;                         \
    float acc_ = 0.f;                                                      \
    _Pragma("unroll") for (int d_ = 0; d_ < 9; ++d_) acc_ =                \
        fmaf(a2[d_], bf2f(vrow_[ch + d_]), acc_);                          \
    acc_ *= inv_s;                                                         \
    if ((OH) < 6 && (OW) < 6)                                              \
      acc_ += bf2f(k1T[(((OH) + 3) * 9 + ((OW) + 3)) * PITCH + 4 + ch]);   \
    if (valid_inst) outb[(OH)*9 + (OW)] = acc_;                            \
  } while (0)

#pragma unroll
  for (int k = 0; k < 4; ++k) {
    int idx = s4 * 4 + k;
    const bool valid_inst = (idx < 15);
    if (!valid_inst) idx = 14;  // dummy recomputes a real instance, no store
    int gh_i = idx / 5, gw_i = idx - (idx / 5) * 5;
    int oh = (s ? 6 : 3) + gh_i;
    int gh = s ? ((gh_i + 4) % 5) : (gh_i + 1);
    int g9 = __builtin_amdgcn_readfirstlane((gh * 5 + gw_i) * 9);

    // kq gather via premultiplied pixtab (zero-row kills validity selects)
    float kq[18];
#pragma unroll
    for (int q = 0; q < 9; ++q) {
      int off = (int)pixtab[g9 + tq[q]] + cq[q];
      kq[q] = bf2f(xT[off]);
      kq[9 + q] = bf2f(k1T[off]);
    }

    __builtin_amdgcn_s_setprio(1);
    // w1 -> folded BN -> ReLU
    float r[9];
#pragma unroll
    for (int o = 0; o < 9; ++o) {
      int m = g9 + o;
      const float* w1m = w1 + m * 18;
      float a = 0.f;
#pragma unroll
      for (int i2 = 0; i2 < 18; ++i2) a = fmaf(w1m[i2], kq[i2], a);
      float2 bn = bnf[m];
      a = fmaf(a, bn.x, bn.y);
      r[o] = fmaxf(a, 0.f);
    }

    // w2 + b2 -> softmax (registers)
    float a2[9], mx = -1e30f;
#pragma unroll
    for (int d = 0; d < 9; ++d) {
      int m = g9 + d;
      const float* w2m = w2 + m * 9;
      float a = b2[m];
#pragma unroll
      for (int o = 0; o < 9; ++o) a = fmaf(w2m[o], r[o], a);
      a2[d] = a;
      mx = fmaxf(mx, a);
    }
    float ssum = 0.f;
#pragma unroll
    for (int d = 0; d < 9; ++d) {
      a2[d] = __expf(a2[d] - mx);
      ssum += a2[d];
    }
    float inv_s = __builtin_amdgcn_rcpf(ssum);
    __builtin_amdgcn_s_setprio(0);

    // PV + k1-add + store; gw==1 serves both ow=3 and ow=8
    int ow0 = (gw_i == 0) ? 7 : (gw_i + 2);
    PV_STORE(oh, ow0);
    if (gw_i == 1) PV_STORE(oh, 8);
  }
#undef PV_STORE

  // ---- epilogue: non-PV output pixels
  if (s == 0) {
    if (s4 < 3) {
      int oh = s4;  // rows 0..2: k1 where ow<6, else 0
#pragma unroll
      for (int ow = 0; ow < 9; ++ow) {
        float v2 = 0.f;
        if (ow < 6)
          v2 = bf2f(k1T[((oh + 3) * 9 + (ow + 3)) * PITCH + 4 + ch]);
        outb[oh * 9 + ow] = v2;
      }
    } else {
      // rows 3..5, cols 0..2: k1-only
#pragma unroll
      for (int r0 = 0; r0 < 3; ++r0) {
        int oh = 3 + r0;
#pragma unroll
        for (int ow = 0; ow < 3; ++ow)
          outb[oh * 9 + ow] =
              bf2f(k1T[((oh + 3) * 9 + (ow + 3)) * PITCH + 4 + ch]);
      }
    }
  } else if (s4 < 3) {
    int oh = 6 + s4;  // rows 6..8, cols 0..2: zero
    outb[oh * 9 + 0] = 0.f;
    outb[oh * 9 + 1] = 0.f;
    outb[oh * 9 + 2] = 0.f;
  }
}

extern "C" void kernel_launch(void* const* d_in, const int* in_sizes, int n_in,
                              void* d_out, int out_size, void* d_ws, size_t ws_size,
                              hipStream_t stream) {
  const float* x     = (const float*)d_in[0];
  const float* wk    = (const float*)d_in[1];
  const float* bk    = (const float*)d_in[2];
  const float* w1    = (const float*)d_in[3];
  const float* gamma = (const float*)d_in[4];
  const float* beta  = (const float*)d_in[5];
  const float* mean  = (const float*)d_in[6];
  const float* var   = (const float*)d_in[7];
  const float* w2    = (const float*)d_in[8];
  const float* b2    = (const float*)d_in[9];
  const float* wv    = (const float*)d_in[10];
  const float* bv    = (const float*)d_in[11];
  float* out = (float*)d_out;

  hipLaunchKernelGGL(semca_fused, dim3(256), dim3(1024), 0, stream,
                     x, wk, bk, w1, gamma, beta, mean, var, w2, b2, wv, bv, out);
}

// Round 3
// 27.735 us; speedup vs baseline: 1.0081x; 1.0081x over previous
//
#include <hip/hip_runtime.h>

#define C 256
#define HW 81
#define PITCH 292   // ushorts per pixel row: [4 pad][256 ch][32 pad] (even dword pitch)
#define PITCHD 146  // dwords per pixel row; 146%32=18 -> gather tap bases ~4-apart
#define ZROW 81     // zeroed row index for invalid gather taps

__device__ __forceinline__ float lo_f(unsigned int d) {
  union { unsigned int i; float f; } c; c.i = d << 16; return c.f;
}
__device__ __forceinline__ float hi_f(unsigned int d) {
  union { unsigned int i; float f; } c; c.i = d & 0xffff0000u; return c.f;
}
__device__ __forceinline__ float bf2f(unsigned short u) {
  union { unsigned int i; float f; } c; c.i = ((unsigned int)u) << 16; return c.f;
}
__device__ __forceinline__ unsigned short f2bf(float f) {
  union { float f; unsigned int i; } c; c.f = f;
  return (unsigned short)((c.i + 0x7fffu + ((c.i >> 16) & 1u)) >> 16);
}
__device__ __forceinline__ unsigned int pack2(float a, float b) {
  return (unsigned int)f2bf(a) | ((unsigned int)f2bf(b) << 16);
}

// ---------------------------------------------------------------------------
// Fully fused SeMCA. Block = (b, s): s=0 -> output rows 0..5, s=1 -> rows 6..8.
// 1024 threads = 4 instance-slots x 256 channels. 2 barriers.
// R3 = R2 with the phase-1a base-pointer fix (window starts at row base, so
// e[0] is channel 4u-4 via the left pad; R2 erroneously started at +2 dwords,
// shifting the conv AND reading uninitialized pad ushorts 264..267).
// R2 theory under test: LDS-pipe bound ->
//  - PITCHD 133 -> 146: phase-2 gather tap-pixel bank bases go from three
//    3-way-overlapping clusters to an even ~4-apart tiling (one 2-way dup).
//  - phase 1a width-4: 3x ds_read_b64 + 1x ds_write_b64 per 4 channels.
// ---------------------------------------------------------------------------
__global__ __launch_bounds__(1024) void semca_fused(
    const float* __restrict__ x, const float* __restrict__ wk,
    const float* __restrict__ bk, const float* __restrict__ w1,
    const float* __restrict__ gamma, const float* __restrict__ beta,
    const float* __restrict__ mean, const float* __restrict__ var,
    const float* __restrict__ w2, const float* __restrict__ b2,
    const float* __restrict__ wv, const float* __restrict__ bv,
    float* __restrict__ out) {
  __shared__ unsigned short xT[82 * PITCH];   // 47,888 B (row 81 = zeros)
  __shared__ unsigned short k1T[82 * PITCH];  // 47,888 B (row 81 = zeros)
  __shared__ unsigned short vT[18 * PITCH];   // 10,512 B
  __shared__ unsigned short pixtab[228];      //    456 B (premultiplied by PITCH)
  __shared__ float2 bnf[225];                 //  1,800 B  (~106 KiB total)

  const int blk = blockIdx.x;
  const int b = (blk & 7) * 16 + ((blk >> 3) & 15);  // XCD-paired, bijective
  const int s = blk >> 7;
  const int tid = threadIdx.x;
  const float* xb = x + (size_t)b * (C * HW);

  unsigned int* xTd = (unsigned int*)xT;
  unsigned int* k1Td = (unsigned int*)k1T;
  unsigned int* vTd = (unsigned int*)vT;

  // ---- phase 0: stage x (bf16, ch-pair packed dwords), tables, zeros
  {
    auto stage = [&](int f) {
      int chp = f / HW;             // channel pair 0..127 (p consecutive/lane)
      int p = f - chp * HW;
      xTd[PITCHD * p + 2 + chp] =
          pack2(xb[(2 * chp) * HW + p], xb[(2 * chp + 1) * HW + p]);
    };
#pragma unroll
    for (int rep = 0; rep < 10; ++rep) stage(tid + rep * 1024);
    if (tid < 128) stage(10240 + tid);
  }
  for (int t = tid; t < 810; t += 1024) {  // x channel-pad zeros
    int p = t / 10, k2 = t - (t / 10) * 10;
    xT[p * PITCH + ((k2 < 4) ? k2 : (256 + k2))] = 0;
  }
  if (tid < PITCHD) {                      // zero row 81 of xT and k1T
    xTd[PITCHD * ZROW + tid] = 0;
    k1Td[PITCHD * ZROW + tid] = 0;
  }
  for (int t = tid; t < 225; t += 1024) {  // pixtab (premul) + folded BN
    int g = t / 9, tap = t - (t / 9) * 9;
    int kh = tap / 3, kw = tap - kh * 3;
    int h = kh * 5 + g / 5, w = kw * 5 + (g - (g / 5) * 5);
    pixtab[t] = (h < 9 && w < 9) ? (unsigned short)((h * 9 + w) * PITCH)
                                 : (unsigned short)(ZROW * PITCH);
    float inv = gamma[t] * rsqrtf(var[t] + 1e-5f);
    bnf[t] = make_float2(inv, beta[t] - mean[t] * inv);
  }

  // ---- hoisted phase-1b weights: chv fixed per thread -> registers
  const int chv = tid & 127;
  float wv_e[9], wv_o[9];
#pragma unroll
  for (int t = 0; t < 9; ++t) {
    wv_e[t] = wv[(2 * chv) * 9 + t];
    wv_o[t] = wv[(2 * chv + 1) * 9 + t];
  }
  const float bv_e = bv[2 * chv], bv_o = bv[2 * chv + 1];

  __syncthreads();

  // ---- phase 1a: k1[p][ch] = sum_j x[p][ch+j-4]*wk[p][j] + bk[p]
  // width-4: channels 4u..4u+3 need ushorts 4u..4u+11 (ch-4 halo via left
  // pad) = dwords 2u..2u+5 from the ROW BASE -> 3x ds_read_b64, 1x b64 write.
  {
    auto k1fn = [&](int f) {
      int p = __builtin_amdgcn_readfirstlane(f >> 6);
      int u = f & 63;  // channel quad index
      const uint2* wrow2 = (const uint2*)(xTd + PITCHD * p);
      uint2 q0 = wrow2[u], q1 = wrow2[u + 1], q2 = wrow2[u + 2];
      float e[12] = {lo_f(q0.x), hi_f(q0.x), lo_f(q0.y), hi_f(q0.y),
                     lo_f(q1.x), hi_f(q1.x), lo_f(q1.y), hi_f(q1.y),
                     lo_f(q2.x), hi_f(q2.x), lo_f(q2.y), hi_f(q2.y)};
      const float* wkp = wk + p * 9;  // scalar loads (p uniform)
      float bkp = bk[p];
      float c0 = bkp, c1 = bkp, c2 = bkp, c3 = bkp;
#pragma unroll
      for (int j = 0; j < 9; ++j) {
        float wj = wkp[j];
        c0 = fmaf(wj, e[j], c0);
        c1 = fmaf(wj, e[j + 1], c1);
        c2 = fmaf(wj, e[j + 2], c2);
        c3 = fmaf(wj, e[j + 3], c3);
      }
      *(uint2*)(k1Td + PITCHD * p + 2 + 2 * u) =
          make_uint2(pack2(c0, c1), pack2(c2, c3));
    };
#pragma unroll
    for (int rep = 0; rep < 5; ++rep) k1fn(tid + rep * 1024);
    if (tid < 64) k1fn(5120 + tid);
  }

  // ---- phase 1b: v (3x3 depthwise) at the 18 pixels this half needs
  {
    auto vfn = [&](int f) {
      int e = __builtin_amdgcn_readfirstlane(f >> 7);  // 0..17 uniform
      int r0 = e / 6;
      int i = s * 3 + r0;  // v-pixel row 0..5
      int j = e - r0 * 6;  // v-pixel col 0..5
      float a_e = bv_e, a_o = bv_o;
#pragma unroll
      for (int di = 0; di < 3; ++di) {
        int ii = i + di - 1;
        if (ii < 0) continue;  // ii <= 6 < 9 always
#pragma unroll
        for (int dj = 0; dj < 3; ++dj) {
          int jj = j + dj - 1;
          if (jj < 0) continue;  // jj <= 6 < 9 always
          unsigned int d = xTd[PITCHD * (ii * 9 + jj) + 2 + chv];
          int t = di * 3 + dj;
          a_e = fmaf(lo_f(d), wv_e[t], a_e);
          a_o = fmaf(hi_f(d), wv_o[t], a_o);
        }
      }
      vTd[PITCHD * e + 2 + chv] = pack2(a_e, a_o);
    };
#pragma unroll
    for (int rep = 0; rep < 2; ++rep) vfn(tid + rep * 1024);
    if (tid < 256) vfn(2048 + tid);
  }
  if (tid < 180) {  // vT channel-pad zeros
    int e = tid / 10, k2 = tid - (tid / 10) * 10;
    vT[e * PITCH + ((k2 < 4) ? k2 : (256 + k2))] = 0;
  }
  __syncthreads();

  // ---- phase 2: 15 deduped instances; 4 slots x 4 unrolled iterations
  const int s4 = tid >> 8;  // slot 0..3 (wave-uniform)
  const int ch = tid & 255;
  const int ci0 = ch / 9;
  const int tap0 = ch - ci0 * 9;
  float* outb = out + ((size_t)b * C + ch) * HW;

  // per-lane gather walk is instance-invariant: hoist out of the k-loop
  int tq[9], cq[9];
  {
    int ci = ci0, tap = tap0;
#pragma unroll
    for (int q = 0; q < 9; ++q) {
      tq[q] = tap;
      cq[q] = 4 + ci;
      tap += 4;
      ci += 28;
      if (tap >= 9) { tap -= 9; ci += 1; }
    }
  }

#define PV_STORE(OH, OW)                                                   \
  do {                                                                     \
    int e_ = gh_i * 6 + ((OW)-3);                                          \
    const unsigned short* vrow_ = vT + e_ * PITCH;                         \
    float acc_ = 0.f;                                                      \
    _Pragma("unroll") for (int d_ = 0; d_ < 9; ++d_) acc_ =                \
        fmaf(a2[d_], bf2f(vrow_[ch + d_]), acc_);                          \
    acc_ *= inv_s;                                                         \
    if ((OH) < 6 && (OW) < 6)                                              \
      acc_ += bf2f(k1T[(((OH) + 3) * 9 + ((OW) + 3)) * PITCH + 4 + ch]);   \
    if (valid_inst) outb[(OH)*9 + (OW)] = acc_;                            \
  } while (0)

#pragma unroll
  for (int k = 0; k < 4; ++k) {
    int idx = s4 * 4 + k;
    const bool valid_inst = (idx < 15);
    if (!valid_inst) idx = 14;  // dummy recomputes a real instance, no store
    int gh_i = idx / 5, gw_i = idx - (idx / 5) * 5;
    int oh = (s ? 6 : 3) + gh_i;
    int gh = s ? ((gh_i + 4) % 5) : (gh_i + 1);
    int g9 = __builtin_amdgcn_readfirstlane((gh * 5 + gw_i) * 9);

    // kq gather via premultiplied pixtab (zero-row kills validity selects)
    float kq[18];
#pragma unroll
    for (int q = 0; q < 9; ++q) {
      int off = (int)pixtab[g9 + tq[q]] + cq[q];
      kq[q] = bf2f(xT[off]);
      kq[9 + q] = bf2f(k1T[off]);
    }

    __builtin_amdgcn_s_setprio(1);
    // w1 -> folded BN -> ReLU
    float r[9];
#pragma unroll
    for (int o = 0; o < 9; ++o) {
      int m = g9 + o;
      const float* w1m = w1 + m * 18;
      float a = 0.f;
#pragma unroll
      for (int i2 = 0; i2 < 18; ++i2) a = fmaf(w1m[i2], kq[i2], a);
      float2 bn = bnf[m];
      a = fmaf(a, bn.x, bn.y);
      r[o] = fmaxf(a, 0.f);
    }

    // w2 + b2 -> softmax (registers)
    float a2[9], mx = -1e30f;
#pragma unroll
    for (int d = 0; d < 9; ++d) {
      int m = g9 + d;
      const float* w2m = w2 + m * 9;
      float a = b2[m];
#pragma unroll
      for (int o = 0; o < 9; ++o) a = fmaf(w2m[o], r[o], a);
      a2[d] = a;
      mx = fmaxf(mx, a);
    }
    float ssum = 0.f;
#pragma unroll
    for (int d = 0; d < 9; ++d) {
      a2[d] = __expf(a2[d] - mx);
      ssum += a2[d];
    }
    float inv_s = __builtin_amdgcn_rcpf(ssum);
    __builtin_amdgcn_s_setprio(0);

    // PV + k1-add + store; gw==1 serves both ow=3 and ow=8
    int ow0 = (gw_i == 0) ? 7 : (gw_i + 2);
    PV_STORE(oh, ow0);
    if (gw_i == 1) PV_STORE(oh, 8);
  }
#undef PV_STORE

  // ---- epilogue: non-PV output pixels
  if (s == 0) {
    if (s4 < 3) {
      int oh = s4;  // rows 0..2: k1 where ow<6, else 0
#pragma unroll
      for (int ow = 0; ow < 9; ++ow) {
        float v2 = 0.f;
        if (ow < 6)
          v2 = bf2f(k1T[((oh + 3) * 9 + (ow + 3)) * PITCH + 4 + ch]);
        outb[oh * 9 + ow] = v2;
      }
    } else {
      // rows 3..5, cols 0..2: k1-only
#pragma unroll
      for (int r0 = 0; r0 < 3; ++r0) {
        int oh = 3 + r0;
#pragma unroll
        for (int ow = 0; ow < 3; ++ow)
          outb[oh * 9 + ow] =
              bf2f(k1T[((oh + 3) * 9 + (ow + 3)) * PITCH + 4 + ch]);
      }
    }
  } else if (s4 < 3) {
    int oh = 6 + s4;  // rows 6..8, cols 0..2: zero
    outb[oh * 9 + 0] = 0.f;
    outb[oh * 9 + 1] = 0.f;
    outb[oh * 9 + 2] = 0.f;
  }
}

extern "C" void kernel_launch(void* const* d_in, const int* in_sizes, int n_in,
                              void* d_out, int out_size, void* d_ws, size_t ws_size,
                              hipStream_t stream) {
  const float* x     = (const float*)d_in[0];
  const float* wk    = (const float*)d_in[1];
  const float* bk    = (const float*)d_in[2];
  const float* w1    = (const float*)d_in[3];
  const float* gamma = (const float*)d_in[4];
  const float* beta  = (const float*)d_in[5];
  const float* mean  = (const float*)d_in[6];
  const float* var   = (const float*)d_in[7];
  const float* w2    = (const float*)d_in[8];
  const float* b2    = (const float*)d_in[9];
  const float* wv    = (const float*)d_in[10];
  const float* bv    = (const float*)d_in[11];
  float* out = (float*)d_out;

  hipLaunchKernelGGL(semca_fused, dim3(256), dim3(1024), 0, stream,
                     x, wk, bk, w1, gamma, beta, mean, var, w2, b2, wv, bv, out);
}